// Round 1
// baseline (12173.178 us; speedup 1.0000x reference)
//
#include <hip/hip_runtime.h>

typedef _Float16 f16;
typedef _Float16 f16x8 __attribute__((ext_vector_type(8)));
typedef float f32x4 __attribute__((ext_vector_type(4)));

#define BB 8
#define TT 1024
#define HH 768
#define HDD 384
#define NG 1536        // 4*HDD
#define SS 16
#define MTOT (BB*TT)   // 8192

// ---------------- casts ----------------
__global__ void cast_f32_f16_k(const float* __restrict__ src, f16* __restrict__ dst, int n) {
    int i = blockIdx.x*256 + threadIdx.x;
    if (i < n) dst[i] = (f16)src[i];
}

__global__ void bias_sum_k(const float* a0,const float* b0,const float* a1,const float* b1,
                           const float* a2,const float* b2,const float* a3,const float* b3,
                           float* __restrict__ out) {
    int i = blockIdx.x*256 + threadIdx.x;
    if (i >= 4*NG) return;
    int which = i/NG, j = i - which*NG;
    const float* pa = which==0?a0:which==1?a1:which==2?a2:a3;
    const float* pb = which==0?b0:which==1?b1:which==2?b2:b3;
    out[i] = pa[j] + pb[j];
}

__global__ void embed_cast_k(const int* __restrict__ ids, const float* __restrict__ emb,
                             f16* __restrict__ x) {
    int i = blockIdx.x*256 + threadIdx.x;   // < MTOT*HH
    if (i < MTOT*HH) {
        int m = i / HH;
        int k = i - m*HH;
        x[i] = (f16)emb[(size_t)ids[m]*HH + k];
    }
}

// ---------------- input GEMM: pre[d][m][col] = x[m][:] . W[d][col][:] + bias ----------------
// A: [MTOT][768] f16 row-major.  W: [1536][768] f16 row-major ("B^T" = [N][K]).
// MFMA 16x16x32 f16, assumed layouts: A/B lane frag = (dim=l&15, k=8*(l>>4)+e contiguous),
// C/D: col=l&15, row=4*(l>>4)+r   [m89-verified]
__launch_bounds__(256,1)
__global__ void gemm_pre_k(const f16* __restrict__ A, const f16* __restrict__ Wf,
                           const f16* __restrict__ Wb, const float* __restrict__ bsum2,
                           f16* __restrict__ pre) {
    int d = blockIdx.z;
    const f16* Wt = d ? Wb : Wf;
    const float* bs = bsum2 + d*NG;
    f16* out = pre + (size_t)d*MTOT*NG;
    int m0 = blockIdx.x*64, n0 = blockIdx.y*64;
    __shared__ f16 As[64*72];   // +8 halves pad: stride 144B -> 16B aligned, 2-way banks (free)
    __shared__ f16 Bs[64*72];
    int tid = threadIdx.x;
    int w = tid>>6, l = tid&63;
    int lrow = l&15, lgrp = l>>4;
    int mq = (w>>1)*32, nq = (w&1)*32;
    f32x4 acc00={0,0,0,0}, acc01={0,0,0,0}, acc10={0,0,0,0}, acc11={0,0,0,0};

    for (int k0=0; k0<HH; k0+=64) {
        __syncthreads();
        #pragma unroll
        for (int r=0;r<2;r++) {
            int c = tid + 256*r;
            int row = c>>3, seg = c&7;
            *(f16x8*)(As + row*72 + seg*8) = *(const f16x8*)(A  + ((size_t)(m0+row))*HH + k0 + seg*8);
            *(f16x8*)(Bs + row*72 + seg*8) = *(const f16x8*)(Wt + ((size_t)(n0+row))*HH + k0 + seg*8);
        }
        __syncthreads();
        #pragma unroll
        for (int kk=0; kk<64; kk+=32) {
            f16x8 a0 = *(const f16x8*)(As + (mq+lrow)*72    + kk + lgrp*8);
            f16x8 a1 = *(const f16x8*)(As + (mq+16+lrow)*72 + kk + lgrp*8);
            f16x8 b0 = *(const f16x8*)(Bs + (nq+lrow)*72    + kk + lgrp*8);
            f16x8 b1 = *(const f16x8*)(Bs + (nq+16+lrow)*72 + kk + lgrp*8);
            acc00 = __builtin_amdgcn_mfma_f32_16x16x32_f16(a0,b0,acc00,0,0,0);
            acc01 = __builtin_amdgcn_mfma_f32_16x16x32_f16(a0,b1,acc01,0,0,0);
            acc10 = __builtin_amdgcn_mfma_f32_16x16x32_f16(a1,b0,acc10,0,0,0);
            acc11 = __builtin_amdgcn_mfma_f32_16x16x32_f16(a1,b1,acc11,0,0,0);
        }
    }
    #pragma unroll
    for (int mt=0;mt<2;mt++) {
        #pragma unroll
        for (int nt=0;nt<2;nt++) {
            f32x4 a = (mt==0)?(nt==0?acc00:acc01):(nt==0?acc10:acc11);
            int col = n0 + nq + nt*16 + lrow;
            float bv = bs[col];
            #pragma unroll
            for (int r=0;r<4;r++) {
                int row = m0 + mq + mt*16 + lgrp*4 + r;
                out[(size_t)row*NG + col] = (f16)(a[r] + bv);
            }
        }
    }
}

// ---------------- LSTM recurrence ----------------
// grid = 24 blocks: [0..11] forward chunks, [12..23] backward chunks.
// Block g owns h-slice [32g,32g+32) and gate cols {q*384 + 32g + jh}.
// W_hh B-fragments are register-resident (96 VGPR/lane) for all 1024 steps.
// h exchange: exch[dir][t][kk][lgrp][row<8][e] f16 (A-fragment layout, rows 8..15 implicit zero).
// flags[dir][t]: monotonically counts producers (12 == ready). Never reset -> no ABA.
__launch_bounds__(256,1)
__global__ void lstm_layer_k(const f16* __restrict__ pre,
                             const f16* __restrict__ whh_f,
                             const f16* __restrict__ whh_b,
                             f16* __restrict__ xout,       // [MTOT][768] f16, dir half-offset
                             f16* __restrict__ exch,
                             unsigned* __restrict__ flags) {
    int dir = blockIdx.x / 12;
    int g   = blockIdx.x - dir*12;
    const f16* W    = dir ? whh_b : whh_f;
    const f16* preD = pre  + (size_t)dir*MTOT*NG;
    f16* exchD      = exch + (size_t)dir*TT*3072;
    unsigned* flagD = flags + dir*TT;

    int tid = threadIdx.x;
    int w = tid>>6, l = tid&63;       // wave w == gate index (i,f,g,o)
    int lrow = l&15, lgrp = l>>4;

    // preload W_hh B-frags: rows = w*384 + 32g + {0..31}, k contiguous 8 per lane
    f16x8 bf0[12], bf1[12];
    {
        int row0 = w*HDD + g*32 + lrow;
        #pragma unroll
        for (int kk=0; kk<12; kk++)
            bf0[kk] = *(const f16x8*)(W + (size_t)row0*HDD + kk*32 + lgrp*8);
        int row1 = row0 + 16;
        #pragma unroll
        for (int kk=0; kk<12; kk++)
            bf1[kk] = *(const f16x8*)(W + (size_t)row1*HDD + kk*32 + lgrp*8);
    }

    __shared__ float gatesS[128*9];   // [local col][batch], stride 9 -> conflict-free
    int eb = tid>>5, ejh = tid&31;    // epilogue thread = (batch, jh)
    float c_state = 0.f;
    size_t exch_wr = ((size_t)g*4 + (ejh>>3))*64 + (size_t)eb*8 + (ejh&7);
    size_t mrow = (size_t)eb*TT;

    for (int step=0; step<TT; step++) {
        int t = dir ? (TT-1-step) : step;
        // prefetch pre-activations for this step (land during poll/MFMA)
        const f16* prow = preD + (mrow + t)*NG + g*32 + ejh;
        f16 p0 = prow[0];
        f16 p1 = prow[HDD];
        f16 p2 = prow[2*HDD];
        f16 p3 = prow[3*HDD];

        f32x4 acc0 = {0,0,0,0}, acc1 = {0,0,0,0};
        if (step > 0) {
            if (tid==0) {
                while (__hip_atomic_load(flagD + (step-1), __ATOMIC_ACQUIRE,
                                         __HIP_MEMORY_SCOPE_AGENT) < 12u)
                    __builtin_amdgcn_s_sleep(1);
            }
            __syncthreads();
            const f16* ex = exchD + (size_t)(step-1)*3072;
            #pragma unroll
            for (int kk=0; kk<12; kk++) {
                f16x8 af = {0,0,0,0,0,0,0,0};              // rows 8..15 stay zero
                if (lrow < 8)
                    af = *(const f16x8*)(ex + ((size_t)kk*4 + lgrp)*64 + lrow*8);
                acc0 = __builtin_amdgcn_mfma_f32_16x16x32_f16(af, bf0[kk], acc0, 0,0,0);
                acc1 = __builtin_amdgcn_mfma_f32_16x16x32_f16(af, bf1[kk], acc1, 0,0,0);
            }
        }
        // stage gates (C layout: col=l&15, row=4*lgrp+r; rows>=8 are padding)
        if (lgrp < 2) {
            int col0 = 32*w + lrow;
            #pragma unroll
            for (int r=0;r<4;r++) gatesS[col0*9 + lgrp*4 + r] = acc0[r];
            int col1 = col0 + 16;
            #pragma unroll
            for (int r=0;r<4;r++) gatesS[col1*9 + lgrp*4 + r] = acc1[r];
        }
        __syncthreads();
        float xi = (float)p0 + gatesS[(ejh   )*9 + eb];
        float xf = (float)p1 + gatesS[(32+ejh)*9 + eb];
        float xg = (float)p2 + gatesS[(64+ejh)*9 + eb];
        float xo = (float)p3 + gatesS[(96+ejh)*9 + eb];
        float si = 1.f/(1.f+__expf(-xi));
        float sf = 1.f/(1.f+__expf(-xf));
        float gg = tanhf(xg);
        float so = 1.f/(1.f+__expf(-xo));
        c_state = sf*c_state + si*gg;
        float h = so*tanhf(c_state);
        f16 hh = (f16)h;
        xout[(mrow + t)*HH + dir*HDD + g*32 + ejh] = hh;
        exchD[(size_t)step*3072 + exch_wr] = hh;
        __syncthreads();   // drains each wave's vmem (s_waitcnt vmcnt(0) before s_barrier)
        if (tid == 0) {
            __threadfence();  // agent-scope writeback so other XCDs see the plain stores
            __hip_atomic_fetch_add(flagD + step, 1u, __ATOMIC_RELEASE,
                                   __HIP_MEMORY_SCOPE_AGENT);
        }
    }
}

// ---------------- segment mean pool + MLP + sigmoid ----------------
__global__ void pool_mlp_k(const f16* __restrict__ enc, const int* __restrict__ bounds,
                           const float* __restrict__ w1, const float* __restrict__ b1,
                           const float* __restrict__ w2, const float* __restrict__ b2,
                           float* __restrict__ out) {
    int b = blockIdx.x >> 4, s = blockIdx.x & 15;
    int tid = threadIdx.x;
    int e  = bounds[b*SS + s];
    int st = (s==0) ? 0 : bounds[b*SS + s - 1];
    int len = e - st; if (len < 1) len = 1;
    __shared__ float meanS[HH];
    __shared__ float hS[HDD];
    __shared__ float redS[256];
    for (int dd = tid; dd < HH; dd += 256) {
        float a = 0.f;
        for (int t = st; t < e; t++) a += (float)enc[((size_t)b*TT + t)*HH + dd];
        meanS[dd] = a / (float)len;
    }
    __syncthreads();
    for (int j = tid; j < HDD; j += 256) {
        float a = b1[j];
        const float* wr = w1 + (size_t)j*HH;
        for (int dd = 0; dd < HH; dd++) a += meanS[dd]*wr[dd];
        hS[j] = a > 0.f ? a : 0.f;
    }
    __syncthreads();
    float p = 0.f;
    for (int j = tid; j < HDD; j += 256) p += hS[j]*w2[j];
    redS[tid] = p;
    __syncthreads();
    for (int o = 128; o > 0; o >>= 1) {
        if (tid < o) redS[tid] += redS[tid+o];
        __syncthreads();
    }
    if (tid == 0) {
        float r = 1.f/(1.f+__expf(-(redS[0] + b2[0])));
        out[b*SS + s] = r;
    }
}

__global__ void finalize_k(float* __restrict__ out) {
    int b = threadIdx.x;
    if (b < BB) {
        float m = 1e30f;
        for (int s=0;s<SS;s++) {
            float r = out[b*SS+s];
            float mask = (r > 0.f) ? 1.f : 0.f;
            float v = r*mask + (1.f-mask);
            m = fminf(m, v);
        }
        out[BB*SS + b] = m;
    }
}

extern "C" void kernel_launch(void* const* d_in, const int* in_sizes, int n_in,
                              void* d_out, int out_size, void* d_ws, size_t ws_size,
                              hipStream_t stream) {
    const int*   ids    = (const int*)d_in[0];
    const int*   bounds = (const int*)d_in[1];
    const float* emb    = (const float*)d_in[2];
    const float* wih[4]; const float* whh[4]; const float* bih[4]; const float* bhh[4];
    for (int i=0;i<4;i++) {                // order: l0f, l0b, l1f, l1b
        wih[i] = (const float*)d_in[3 + 4*i];
        whh[i] = (const float*)d_in[4 + 4*i];
        bih[i] = (const float*)d_in[5 + 4*i];
        bhh[i] = (const float*)d_in[6 + 4*i];
    }
    const float* w1 = (const float*)d_in[19];
    const float* b1 = (const float*)d_in[20];
    const float* w2 = (const float*)d_in[21];
    const float* b2 = (const float*)d_in[22];
    float* out = (float*)d_out;

    char* ws = (char*)d_ws;
    size_t off = 0;
    auto alloc = [&](size_t bytes) -> void* {
        void* p = ws + off;
        off += (bytes + 255) & ~(size_t)255;
        return p;
    };
    f16* x0    = (f16*)alloc((size_t)MTOT*HH*2);      // layer0 input; reused as enc
    f16* x1    = (f16*)alloc((size_t)MTOT*HH*2);      // layer0 output / layer1 input
    f16* pre   = (f16*)alloc((size_t)2*MTOT*NG*2);    // pre-activations (reused per layer)
    f16* exch  = (f16*)alloc((size_t)2*TT*3072*2);    // h exchange (reused per layer)
    f16* wihh[4]; for (int i=0;i<4;i++) wihh[i] = (f16*)alloc((size_t)NG*HH*2);
    f16* whhh[4]; for (int i=0;i<4;i++) whhh[i] = (f16*)alloc((size_t)NG*HDD*2);
    float* bsum = (float*)alloc((size_t)4*NG*4);
    unsigned* flags = (unsigned*)alloc((size_t)2*2*TT*4);   // [layer][dir][t]
    f16* enc = x0;

    hipMemsetAsync(flags, 0, 2*2*TT*4, stream);
    for (int i=0;i<4;i++)
        cast_f32_f16_k<<<(NG*HH+255)/256,256,0,stream>>>(wih[i], wihh[i], NG*HH);
    for (int i=0;i<4;i++)
        cast_f32_f16_k<<<(NG*HDD+255)/256,256,0,stream>>>(whh[i], whhh[i], NG*HDD);
    bias_sum_k<<<(4*NG+255)/256,256,0,stream>>>(bih[0],bhh[0],bih[1],bhh[1],
                                                bih[2],bhh[2],bih[3],bhh[3],bsum);
    embed_cast_k<<<(MTOT*HH+255)/256,256,0,stream>>>(ids, emb, x0);

    dim3 gg(MTOT/64, NG/64, 2);
    gemm_pre_k<<<gg,256,0,stream>>>(x0, wihh[0], wihh[1], bsum, pre);
    lstm_layer_k<<<24,256,0,stream>>>(pre, whhh[0], whhh[1], x1, exch, flags);
    gemm_pre_k<<<gg,256,0,stream>>>(x1, wihh[2], wihh[3], bsum + 2*NG, pre);
    lstm_layer_k<<<24,256,0,stream>>>(pre, whhh[2], whhh[3], enc, exch, flags + 2*TT);
    pool_mlp_k<<<BB*SS,256,0,stream>>>(enc, bounds, w1, b1, w2, b2, out);
    finalize_k<<<1,64,0,stream>>>(out);
}

// Round 2
// 12075.510 us; speedup vs baseline: 1.0081x; 1.0081x over previous
//
#include <hip/hip_runtime.h>

typedef _Float16 f16;
typedef _Float16 f16x8 __attribute__((ext_vector_type(8)));
typedef float f32x4 __attribute__((ext_vector_type(4)));

#define BB 8
#define TT 1024
#define HH 768
#define HDD 384
#define NG 1536        // 4*HDD
#define SS 16
#define MTOT (BB*TT)   // 8192

// ---------------- casts ----------------
__global__ void cast_f32_f16_k(const float* __restrict__ src, f16* __restrict__ dst, int n) {
    int i = blockIdx.x*256 + threadIdx.x;
    if (i < n) dst[i] = (f16)src[i];
}

__global__ void bias_sum_k(const float* a0,const float* b0,const float* a1,const float* b1,
                           const float* a2,const float* b2,const float* a3,const float* b3,
                           float* __restrict__ out) {
    int i = blockIdx.x*256 + threadIdx.x;
    if (i >= 4*NG) return;
    int which = i/NG, j = i - which*NG;
    const float* pa = which==0?a0:which==1?a1:which==2?a2:a3;
    const float* pb = which==0?b0:which==1?b1:which==2?b2:b3;
    out[i] = pa[j] + pb[j];
}

__global__ void embed_cast_k(const int* __restrict__ ids, const float* __restrict__ emb,
                             f16* __restrict__ x) {
    int i = blockIdx.x*256 + threadIdx.x;   // < MTOT*HH
    if (i < MTOT*HH) {
        int m = i / HH;
        int k = i - m*HH;
        x[i] = (f16)emb[(size_t)ids[m]*HH + k];
    }
}

// ---------------- input GEMM (validated in R1, unchanged) ----------------
__launch_bounds__(256,1)
__global__ void gemm_pre_k(const f16* __restrict__ A, const f16* __restrict__ Wf,
                           const f16* __restrict__ Wb, const float* __restrict__ bsum2,
                           f16* __restrict__ pre) {
    int d = blockIdx.z;
    const f16* Wt = d ? Wb : Wf;
    const float* bs = bsum2 + d*NG;
    f16* out = pre + (size_t)d*MTOT*NG;
    int m0 = blockIdx.x*64, n0 = blockIdx.y*64;
    __shared__ f16 As[64*72];
    __shared__ f16 Bs[64*72];
    int tid = threadIdx.x;
    int w = tid>>6, l = tid&63;
    int lrow = l&15, lgrp = l>>4;
    int mq = (w>>1)*32, nq = (w&1)*32;
    f32x4 acc00={0,0,0,0}, acc01={0,0,0,0}, acc10={0,0,0,0}, acc11={0,0,0,0};

    for (int k0=0; k0<HH; k0+=64) {
        __syncthreads();
        #pragma unroll
        for (int r=0;r<2;r++) {
            int c = tid + 256*r;
            int row = c>>3, seg = c&7;
            *(f16x8*)(As + row*72 + seg*8) = *(const f16x8*)(A  + ((size_t)(m0+row))*HH + k0 + seg*8);
            *(f16x8*)(Bs + row*72 + seg*8) = *(const f16x8*)(Wt + ((size_t)(n0+row))*HH + k0 + seg*8);
        }
        __syncthreads();
        #pragma unroll
        for (int kk=0; kk<64; kk+=32) {
            f16x8 a0 = *(const f16x8*)(As + (mq+lrow)*72    + kk + lgrp*8);
            f16x8 a1 = *(const f16x8*)(As + (mq+16+lrow)*72 + kk + lgrp*8);
            f16x8 b0 = *(const f16x8*)(Bs + (nq+lrow)*72    + kk + lgrp*8);
            f16x8 b1 = *(const f16x8*)(Bs + (nq+16+lrow)*72 + kk + lgrp*8);
            acc00 = __builtin_amdgcn_mfma_f32_16x16x32_f16(a0,b0,acc00,0,0,0);
            acc01 = __builtin_amdgcn_mfma_f32_16x16x32_f16(a0,b1,acc01,0,0,0);
            acc10 = __builtin_amdgcn_mfma_f32_16x16x32_f16(a1,b0,acc10,0,0,0);
            acc11 = __builtin_amdgcn_mfma_f32_16x16x32_f16(a1,b1,acc11,0,0,0);
        }
    }
    #pragma unroll
    for (int mt=0;mt<2;mt++) {
        #pragma unroll
        for (int nt=0;nt<2;nt++) {
            f32x4 a = (mt==0)?(nt==0?acc00:acc01):(nt==0?acc10:acc11);
            int col = n0 + nq + nt*16 + lrow;
            float bv = bs[col];
            #pragma unroll
            for (int r=0;r<4;r++) {
                int row = m0 + mq + mt*16 + lgrp*4 + r;
                out[(size_t)row*NG + col] = (f16)(a[r] + bv);
            }
        }
    }
}

// ---------------- LSTM recurrence ----------------
// 24 blocks: [0..11] fwd chunks, [12..23] bwd chunks. Block g owns h[32g..32g+32).
// R2 sync protocol (R1 post-mortem: fetch_add on one line from 8 XCDs serialized;
// ACQUIRE poll spammed whole-L2 buffer_inv per iteration):
//   - per-producer flags, 4KB apart: flagD[p*TT + t], written ONCE (no RMW, no ABA)
//   - producer: exch stores -> barrier (vmcnt drain) -> tid0: release fence (wbl2)
//     + RELAXED agent flag store -> xout store deferred off critical path
//   - consumer: every wave polls lanes 0..11 with RELAXED agent loads (read through
//     to coherence point; no inv per iteration), then ONE acquire fence per step.
//     No barrier between poll and MFMA.
__launch_bounds__(256,1)
__global__ void lstm_layer_k(const f16* __restrict__ pre,
                             const f16* __restrict__ whh_f,
                             const f16* __restrict__ whh_b,
                             f16* __restrict__ xout,
                             f16* __restrict__ exch,
                             unsigned* __restrict__ flags) {
    int dir = blockIdx.x / 12;
    int g   = blockIdx.x - dir*12;
    const f16* W    = dir ? whh_b : whh_f;
    const f16* preD = pre  + (size_t)dir*MTOT*NG;
    f16* exchD      = exch + (size_t)dir*TT*3072;
    unsigned* flagD = flags + dir*12*TT;

    int tid = threadIdx.x;
    int w = tid>>6, l = tid&63;       // wave w == gate index (i,f,g,o)
    int lrow = l&15, lgrp = l>>4;

    // register-resident W_hh B-frags: rows = w*384 + 32g + {0..31}
    f16x8 bf0[12], bf1[12];
    {
        int row0 = w*HDD + g*32 + lrow;
        #pragma unroll
        for (int kk=0; kk<12; kk++)
            bf0[kk] = *(const f16x8*)(W + (size_t)row0*HDD + kk*32 + lgrp*8);
        int row1 = row0 + 16;
        #pragma unroll
        for (int kk=0; kk<12; kk++)
            bf1[kk] = *(const f16x8*)(W + (size_t)row1*HDD + kk*32 + lgrp*8);
    }

    __shared__ float gatesS[128*9];   // [local col][batch], stride 9 conflict-free
    int eb = tid>>5, ejh = tid&31;    // epilogue thread = (batch, jh)
    float c_state = 0.f;
    size_t exch_wr = ((size_t)g*4 + (ejh>>3))*64 + (size_t)eb*8 + (ejh&7);
    size_t mrow = (size_t)eb*TT;

    for (int step=0; step<TT; step++) {
        int t = dir ? (TT-1-step) : step;
        // prefetch pre-activations (in flight during poll)
        const f16* prow = preD + (mrow + t)*NG + g*32 + ejh;
        f16 p0 = prow[0];
        f16 p1 = prow[HDD];
        f16 p2 = prow[2*HDD];
        f16 p3 = prow[3*HDD];

        f32x4 acc0 = {0,0,0,0}, acc1 = {0,0,0,0};
        if (step > 0) {
            // per-wave poll: lanes 0..11 watch the 12 producers' step-1 flags
            unsigned got = (l < 12) ? 0u : 1u;
            const unsigned* fp = flagD + (size_t)l*TT + (step-1);
            while (true) {
                if (!got)
                    got = __hip_atomic_load(fp, __ATOMIC_RELAXED, __HIP_MEMORY_SCOPE_AGENT);
                if (__all(got != 0)) break;
                __builtin_amdgcn_s_sleep(1);
            }
            __builtin_amdgcn_fence(__ATOMIC_ACQUIRE, "agent");   // one inv per wave per step
            const f16* ex = exchD + (size_t)(step-1)*3072;
            #pragma unroll
            for (int kk=0; kk<12; kk++) {
                f16x8 af = {0,0,0,0,0,0,0,0};              // rows 8..15 stay zero
                if (lrow < 8)
                    af = *(const f16x8*)(ex + ((size_t)kk*4 + lgrp)*64 + lrow*8);
                acc0 = __builtin_amdgcn_mfma_f32_16x16x32_f16(af, bf0[kk], acc0, 0,0,0);
                acc1 = __builtin_amdgcn_mfma_f32_16x16x32_f16(af, bf1[kk], acc1, 0,0,0);
            }
        }
        // stage gates (C layout: col=l&15, row=4*lgrp+r; rows>=8 padding)
        if (lgrp < 2) {
            int col0 = 32*w + lrow;
            #pragma unroll
            for (int r=0;r<4;r++) gatesS[col0*9 + lgrp*4 + r] = acc0[r];
            int col1 = col0 + 16;
            #pragma unroll
            for (int r=0;r<4;r++) gatesS[col1*9 + lgrp*4 + r] = acc1[r];
        }
        __syncthreads();                               // (b) gates visible to epilogue
        float xi = (float)p0 + gatesS[(ejh   )*9 + eb];
        float xf = (float)p1 + gatesS[(32+ejh)*9 + eb];
        float xg = (float)p2 + gatesS[(64+ejh)*9 + eb];
        float xo = (float)p3 + gatesS[(96+ejh)*9 + eb];
        float si = 1.f/(1.f+__expf(-xi));
        float sf = 1.f/(1.f+__expf(-xf));
        float gg = tanhf(xg);
        float so = 1.f/(1.f+__expf(-xo));
        c_state = sf*c_state + si*gg;
        float h = so*tanhf(c_state);
        f16 hh = (f16)h;
        exchD[(size_t)step*3072 + exch_wr] = hh;
        __syncthreads();                               // (c) drain all waves' exch stores
        if (tid == 0) {
            __builtin_amdgcn_fence(__ATOMIC_RELEASE, "agent");   // wbl2 -> visible at IF
            __hip_atomic_store(flagD + (size_t)g*TT + step, 1u,
                               __ATOMIC_RELAXED, __HIP_MEMORY_SCOPE_AGENT);
        }
        xout[(mrow + t)*HH + dir*HDD + g*32 + ejh] = hh;   // off critical path
    }
}

// ---------------- segment mean pool + MLP + sigmoid ----------------
__global__ void pool_mlp_k(const f16* __restrict__ enc, const int* __restrict__ bounds,
                           const float* __restrict__ w1, const float* __restrict__ b1,
                           const float* __restrict__ w2, const float* __restrict__ b2,
                           float* __restrict__ out) {
    int b = blockIdx.x >> 4, s = blockIdx.x & 15;
    int tid = threadIdx.x;
    int e  = bounds[b*SS + s];
    int st = (s==0) ? 0 : bounds[b*SS + s - 1];
    int len = e - st; if (len < 1) len = 1;
    __shared__ float meanS[HH];
    __shared__ float hS[HDD];
    __shared__ float redS[256];
    for (int dd = tid; dd < HH; dd += 256) {
        float a = 0.f;
        for (int t = st; t < e; t++) a += (float)enc[((size_t)b*TT + t)*HH + dd];
        meanS[dd] = a / (float)len;
    }
    __syncthreads();
    for (int j = tid; j < HDD; j += 256) {
        float a = b1[j];
        const float* wr = w1 + (size_t)j*HH;
        for (int dd = 0; dd < HH; dd++) a += meanS[dd]*wr[dd];
        hS[j] = a > 0.f ? a : 0.f;
    }
    __syncthreads();
    float p = 0.f;
    for (int j = tid; j < HDD; j += 256) p += hS[j]*w2[j];
    redS[tid] = p;
    __syncthreads();
    for (int o = 128; o > 0; o >>= 1) {
        if (tid < o) redS[tid] += redS[tid+o];
        __syncthreads();
    }
    if (tid == 0) {
        float r = 1.f/(1.f+__expf(-(redS[0] + b2[0])));
        out[b*SS + s] = r;
    }
}

__global__ void finalize_k(float* __restrict__ out) {
    int b = threadIdx.x;
    if (b < BB) {
        float m = 1e30f;
        for (int s=0;s<SS;s++) {
            float r = out[b*SS+s];
            float mask = (r > 0.f) ? 1.f : 0.f;
            float v = r*mask + (1.f-mask);
            m = fminf(m, v);
        }
        out[BB*SS + b] = m;
    }
}

extern "C" void kernel_launch(void* const* d_in, const int* in_sizes, int n_in,
                              void* d_out, int out_size, void* d_ws, size_t ws_size,
                              hipStream_t stream) {
    const int*   ids    = (const int*)d_in[0];
    const int*   bounds = (const int*)d_in[1];
    const float* emb    = (const float*)d_in[2];
    const float* wih[4]; const float* whh[4]; const float* bih[4]; const float* bhh[4];
    for (int i=0;i<4;i++) {                // order: l0f, l0b, l1f, l1b
        wih[i] = (const float*)d_in[3 + 4*i];
        whh[i] = (const float*)d_in[4 + 4*i];
        bih[i] = (const float*)d_in[5 + 4*i];
        bhh[i] = (const float*)d_in[6 + 4*i];
    }
    const float* w1 = (const float*)d_in[19];
    const float* b1 = (const float*)d_in[20];
    const float* w2 = (const float*)d_in[21];
    const float* b2 = (const float*)d_in[22];
    float* out = (float*)d_out;

    char* ws = (char*)d_ws;
    size_t off = 0;
    auto alloc = [&](size_t bytes) -> void* {
        void* p = ws + off;
        off += (bytes + 255) & ~(size_t)255;
        return p;
    };
    f16* x0    = (f16*)alloc((size_t)MTOT*HH*2);      // layer0 input; reused as enc
    f16* x1    = (f16*)alloc((size_t)MTOT*HH*2);      // layer0 output / layer1 input
    f16* pre   = (f16*)alloc((size_t)2*MTOT*NG*2);    // pre-activations (reused per layer)
    f16* exch  = (f16*)alloc((size_t)2*TT*3072*2);    // h exchange (reused; acquire-inv
                                                      // before every read makes reuse safe)
    f16* wihh[4]; for (int i=0;i<4;i++) wihh[i] = (f16*)alloc((size_t)NG*HH*2);
    f16* whhh[4]; for (int i=0;i<4;i++) whhh[i] = (f16*)alloc((size_t)NG*HDD*2);
    float* bsum = (float*)alloc((size_t)4*NG*4);
    // flags: [layer][dir][producer][t], producer-strided 4KB -> no line sharing
    unsigned* flags = (unsigned*)alloc((size_t)2*2*12*TT*4);
    f16* enc = x0;

    hipMemsetAsync(flags, 0, (size_t)2*2*12*TT*4, stream);
    for (int i=0;i<4;i++)
        cast_f32_f16_k<<<(NG*HH+255)/256,256,0,stream>>>(wih[i], wihh[i], NG*HH);
    for (int i=0;i<4;i++)
        cast_f32_f16_k<<<(NG*HDD+255)/256,256,0,stream>>>(whh[i], whhh[i], NG*HDD);
    bias_sum_k<<<(4*NG+255)/256,256,0,stream>>>(bih[0],bhh[0],bih[1],bhh[1],
                                                bih[2],bhh[2],bih[3],bhh[3],bsum);
    embed_cast_k<<<(MTOT*HH+255)/256,256,0,stream>>>(ids, emb, x0);

    dim3 gg(MTOT/64, NG/64, 2);
    gemm_pre_k<<<gg,256,0,stream>>>(x0, wihh[0], wihh[1], bsum, pre);
    lstm_layer_k<<<24,256,0,stream>>>(pre, whhh[0], whhh[1], x1, exch, flags);
    gemm_pre_k<<<gg,256,0,stream>>>(x1, wihh[2], wihh[3], bsum + 2*NG, pre);
    lstm_layer_k<<<24,256,0,stream>>>(pre, whhh[2], whhh[3], enc, exch, flags + 2*12*TT);
    pool_mlp_k<<<BB*SS,256,0,stream>>>(enc, bounds, w1, b1, w2, b2, out);
    finalize_k<<<1,64,0,stream>>>(out);
}

// Round 3
// 10491.908 us; speedup vs baseline: 1.1602x; 1.1509x over previous
//
#include <hip/hip_runtime.h>

typedef _Float16 f16;
typedef _Float16 f16x8 __attribute__((ext_vector_type(8)));
typedef float f32x4 __attribute__((ext_vector_type(4)));

#define BB 8
#define TT 1024
#define HH 768
#define HDD 384
#define NG 1536        // 4*HDD
#define SS 16
#define MTOT (BB*TT)   // 8192

// ---------------- casts ----------------
__global__ void cast_f32_f16_k(const float* __restrict__ src, f16* __restrict__ dst, int n) {
    int i = blockIdx.x*256 + threadIdx.x;
    if (i < n) dst[i] = (f16)src[i];
}

__global__ void bias_sum_k(const float* a0,const float* b0,const float* a1,const float* b1,
                           const float* a2,const float* b2,const float* a3,const float* b3,
                           float* __restrict__ out) {
    int i = blockIdx.x*256 + threadIdx.x;
    if (i >= 4*NG) return;
    int which = i/NG, j = i - which*NG;
    const float* pa = which==0?a0:which==1?a1:which==2?a2:a3;
    const float* pb = which==0?b0:which==1?b1:which==2?b2:b3;
    out[i] = pa[j] + pb[j];
}

__global__ void embed_cast_k(const int* __restrict__ ids, const float* __restrict__ emb,
                             f16* __restrict__ x) {
    int i = blockIdx.x*256 + threadIdx.x;   // < MTOT*HH
    if (i < MTOT*HH) {
        int m = i / HH;
        int k = i - m*HH;
        x[i] = (f16)emb[(size_t)ids[m]*HH + k];
    }
}

// ---------------- input GEMM (validated in R1, unchanged) ----------------
__launch_bounds__(256,1)
__global__ void gemm_pre_k(const f16* __restrict__ A, const f16* __restrict__ Wf,
                           const f16* __restrict__ Wb, const float* __restrict__ bsum2,
                           f16* __restrict__ pre) {
    int d = blockIdx.z;
    const f16* Wt = d ? Wb : Wf;
    const float* bs = bsum2 + d*NG;
    f16* out = pre + (size_t)d*MTOT*NG;
    int m0 = blockIdx.x*64, n0 = blockIdx.y*64;
    __shared__ f16 As[64*72];
    __shared__ f16 Bs[64*72];
    int tid = threadIdx.x;
    int w = tid>>6, l = tid&63;
    int lrow = l&15, lgrp = l>>4;
    int mq = (w>>1)*32, nq = (w&1)*32;
    f32x4 acc00={0,0,0,0}, acc01={0,0,0,0}, acc10={0,0,0,0}, acc11={0,0,0,0};

    for (int k0=0; k0<HH; k0+=64) {
        __syncthreads();
        #pragma unroll
        for (int r=0;r<2;r++) {
            int c = tid + 256*r;
            int row = c>>3, seg = c&7;
            *(f16x8*)(As + row*72 + seg*8) = *(const f16x8*)(A  + ((size_t)(m0+row))*HH + k0 + seg*8);
            *(f16x8*)(Bs + row*72 + seg*8) = *(const f16x8*)(Wt + ((size_t)(n0+row))*HH + k0 + seg*8);
        }
        __syncthreads();
        #pragma unroll
        for (int kk=0; kk<64; kk+=32) {
            f16x8 a0 = *(const f16x8*)(As + (mq+lrow)*72    + kk + lgrp*8);
            f16x8 a1 = *(const f16x8*)(As + (mq+16+lrow)*72 + kk + lgrp*8);
            f16x8 b0 = *(const f16x8*)(Bs + (nq+lrow)*72    + kk + lgrp*8);
            f16x8 b1 = *(const f16x8*)(Bs + (nq+16+lrow)*72 + kk + lgrp*8);
            acc00 = __builtin_amdgcn_mfma_f32_16x16x32_f16(a0,b0,acc00,0,0,0);
            acc01 = __builtin_amdgcn_mfma_f32_16x16x32_f16(a0,b1,acc01,0,0,0);
            acc10 = __builtin_amdgcn_mfma_f32_16x16x32_f16(a1,b0,acc10,0,0,0);
            acc11 = __builtin_amdgcn_mfma_f32_16x16x32_f16(a1,b1,acc11,0,0,0);
        }
    }
    #pragma unroll
    for (int mt=0;mt<2;mt++) {
        #pragma unroll
        for (int nt=0;nt<2;nt++) {
            f32x4 a = (mt==0)?(nt==0?acc00:acc01):(nt==0?acc10:acc11);
            int col = n0 + nq + nt*16 + lrow;
            float bv = bs[col];
            #pragma unroll
            for (int r=0;r<4;r++) {
                int row = m0 + mq + mt*16 + lgrp*4 + r;
                out[(size_t)row*NG + col] = (f16)(a[r] + bv);
            }
        }
    }
}

// ---------------- LSTM recurrence ----------------
// 24 blocks: [0..11] fwd chunks, [12..23] bwd chunks. Block g owns h[32g..32g+32).
// R3 sync protocol (R2 post-mortem: the constant was the per-step agent fences —
// release=buffer_wbl2 (flush whole 4MB L2) + acquire=buffer_inv (invalidate L2,
// also re-fetching pre from HBM every step => 112MB FETCH). Fix: NO fences at all;
// every cross-block datum moves via sc1 accesses that hit the coherence point (IF):
//   - producer: exch written as relaxed agent atomic 4B stores (write-through to IF);
//     __syncthreads()'s vmcnt(0) waits for the IF acks; then relaxed agent flag store.
//   - consumer: poll flags with relaxed agent loads, then read exch with relaxed
//     agent atomic 8B loads (bypass stale L1/L2). No buffer_inv, pre stays cached.
__launch_bounds__(256,1)
__global__ void lstm_layer_k(const f16* __restrict__ pre,
                             const f16* __restrict__ whh_f,
                             const f16* __restrict__ whh_b,
                             f16* __restrict__ xout,
                             f16* __restrict__ exch,
                             unsigned* __restrict__ flags) {
    int dir = blockIdx.x / 12;
    int g   = blockIdx.x - dir*12;
    const f16* W    = dir ? whh_b : whh_f;
    const f16* preD = pre  + (size_t)dir*MTOT*NG;
    f16* exchD      = exch + (size_t)dir*TT*3072;
    unsigned* flagD = flags + dir*12*TT;

    int tid = threadIdx.x;
    int w = tid>>6, l = tid&63;       // wave w == gate index (i,f,g,o)
    int lrow = l&15, lgrp = l>>4;

    // register-resident W_hh B-frags: rows = w*384 + 32g + {0..31}
    f16x8 bf0[12], bf1[12];
    {
        int row0 = w*HDD + g*32 + lrow;
        #pragma unroll
        for (int kk=0; kk<12; kk++)
            bf0[kk] = *(const f16x8*)(W + (size_t)row0*HDD + kk*32 + lgrp*8);
        int row1 = row0 + 16;
        #pragma unroll
        for (int kk=0; kk<12; kk++)
            bf1[kk] = *(const f16x8*)(W + (size_t)row1*HDD + kk*32 + lgrp*8);
    }

    __shared__ float gatesS[128*9];   // [local col][batch], stride 9 conflict-free
    int eb = tid>>5, ejh = tid&31;    // epilogue thread = (batch, jh)
    float c_state = 0.f;
    size_t exch_wr = ((size_t)g*4 + (ejh>>3))*64 + (size_t)eb*8 + (ejh&7);
    size_t mrow = (size_t)eb*TT;

    for (int step=0; step<TT; step++) {
        int t = dir ? (TT-1-step) : step;
        // prefetch pre-activations (in flight during poll; stays L2-cached now)
        const f16* prow = preD + (mrow + t)*NG + g*32 + ejh;
        f16 p0 = prow[0];
        f16 p1 = prow[HDD];
        f16 p2 = prow[2*HDD];
        f16 p3 = prow[3*HDD];

        f32x4 acc0 = {0,0,0,0}, acc1 = {0,0,0,0};
        if (step > 0) {
            // per-wave poll: lanes 0..11 watch the 12 producers' step-1 flags
            unsigned got = (l < 12) ? 0u : 1u;
            const unsigned* fp = flagD + (size_t)l*TT + (step-1);
            while (true) {
                if (!got)
                    got = __hip_atomic_load(fp, __ATOMIC_RELAXED, __HIP_MEMORY_SCOPE_AGENT);
                if (__all(got != 0)) break;
                __builtin_amdgcn_s_sleep(1);
            }
            // NO acquire fence: data loads below are sc1 (read IF directly)
            const f16* ex = exchD + (size_t)(step-1)*3072;
            #pragma unroll
            for (int kk=0; kk<12; kk++) {
                f16x8 af = {0,0,0,0,0,0,0,0};              // rows 8..15 stay zero
                if (lrow < 8) {
                    const unsigned long long* q =
                        (const unsigned long long*)(ex + ((size_t)kk*4 + lgrp)*64 + lrow*8);
                    union { unsigned long long u[2]; f16x8 v; } cv;
                    cv.u[0] = __hip_atomic_load(q,     __ATOMIC_RELAXED, __HIP_MEMORY_SCOPE_AGENT);
                    cv.u[1] = __hip_atomic_load(q + 1, __ATOMIC_RELAXED, __HIP_MEMORY_SCOPE_AGENT);
                    af = cv.v;
                }
                acc0 = __builtin_amdgcn_mfma_f32_16x16x32_f16(af, bf0[kk], acc0, 0,0,0);
                acc1 = __builtin_amdgcn_mfma_f32_16x16x32_f16(af, bf1[kk], acc1, 0,0,0);
            }
        }
        // stage gates (C layout: col=l&15, row=4*lgrp+r; rows>=8 padding)
        if (lgrp < 2) {
            int col0 = 32*w + lrow;
            #pragma unroll
            for (int r=0;r<4;r++) gatesS[col0*9 + lgrp*4 + r] = acc0[r];
            int col1 = col0 + 16;
            #pragma unroll
            for (int r=0;r<4;r++) gatesS[col1*9 + lgrp*4 + r] = acc1[r];
        }
        __syncthreads();                               // gates visible to epilogue
        float xi = (float)p0 + gatesS[(ejh   )*9 + eb];
        float xf = (float)p1 + gatesS[(32+ejh)*9 + eb];
        float xg = (float)p2 + gatesS[(64+ejh)*9 + eb];
        float xo = (float)p3 + gatesS[(96+ejh)*9 + eb];
        float si = 1.f/(1.f+__expf(-xi));
        float sf = 1.f/(1.f+__expf(-xf));
        float gg = tanhf(xg);
        float so = 1.f/(1.f+__expf(-xo));
        c_state = sf*c_state + si*gg;
        float h = so*tanhf(c_state);
        f16 hh = (f16)h;
        // pack (e even, e odd) pair via shfl and write-through 4B to IF
        union { f16 h2[2]; unsigned short us; } bc; bc.h2[0] = hh;
        unsigned short hu; __builtin_memcpy(&hu, &hh, 2);
        unsigned short pu = (unsigned short)__shfl_xor((int)hu, 1, 64);
        if ((ejh & 1) == 0) {
            unsigned pkt = (unsigned)hu | ((unsigned)pu << 16);
            __hip_atomic_store((unsigned*)(exchD + (size_t)step*3072 + exch_wr), pkt,
                               __ATOMIC_RELAXED, __HIP_MEMORY_SCOPE_AGENT);
        }
        __syncthreads();           // vmcnt(0): all 128 sc1 stores ACKed at IF
        if (tid == 0) {
            __hip_atomic_store(flagD + (size_t)g*TT + step, 1u,
                               __ATOMIC_RELAXED, __HIP_MEMORY_SCOPE_AGENT);
        }
        xout[(mrow + t)*HH + dir*HDD + g*32 + ejh] = hh;   // off critical path, cached
    }
}

// ---------------- segment mean pool + MLP + sigmoid ----------------
__global__ void pool_mlp_k(const f16* __restrict__ enc, const int* __restrict__ bounds,
                           const float* __restrict__ w1, const float* __restrict__ b1,
                           const float* __restrict__ w2, const float* __restrict__ b2,
                           float* __restrict__ out) {
    int b = blockIdx.x >> 4, s = blockIdx.x & 15;
    int tid = threadIdx.x;
    int e  = bounds[b*SS + s];
    int st = (s==0) ? 0 : bounds[b*SS + s - 1];
    int len = e - st; if (len < 1) len = 1;
    __shared__ float meanS[HH];
    __shared__ float hS[HDD];
    __shared__ float redS[256];
    for (int dd = tid; dd < HH; dd += 256) {
        float a = 0.f;
        for (int t = st; t < e; t++) a += (float)enc[((size_t)b*TT + t)*HH + dd];
        meanS[dd] = a / (float)len;
    }
    __syncthreads();
    for (int j = tid; j < HDD; j += 256) {
        float a = b1[j];
        const float* wr = w1 + (size_t)j*HH;
        for (int dd = 0; dd < HH; dd++) a += meanS[dd]*wr[dd];
        hS[j] = a > 0.f ? a : 0.f;
    }
    __syncthreads();
    float p = 0.f;
    for (int j = tid; j < HDD; j += 256) p += hS[j]*w2[j];
    redS[tid] = p;
    __syncthreads();
    for (int o = 128; o > 0; o >>= 1) {
        if (tid < o) redS[tid] += redS[tid+o];
        __syncthreads();
    }
    if (tid == 0) {
        float r = 1.f/(1.f+__expf(-(redS[0] + b2[0])));
        out[b*SS + s] = r;
    }
}

__global__ void finalize_k(float* __restrict__ out) {
    int b = threadIdx.x;
    if (b < BB) {
        float m = 1e30f;
        for (int s=0;s<SS;s++) {
            float r = out[b*SS+s];
            float mask = (r > 0.f) ? 1.f : 0.f;
            float v = r*mask + (1.f-mask);
            m = fminf(m, v);
        }
        out[BB*SS + b] = m;
    }
}

extern "C" void kernel_launch(void* const* d_in, const int* in_sizes, int n_in,
                              void* d_out, int out_size, void* d_ws, size_t ws_size,
                              hipStream_t stream) {
    const int*   ids    = (const int*)d_in[0];
    const int*   bounds = (const int*)d_in[1];
    const float* emb    = (const float*)d_in[2];
    const float* wih[4]; const float* whh[4]; const float* bih[4]; const float* bhh[4];
    for (int i=0;i<4;i++) {                // order: l0f, l0b, l1f, l1b
        wih[i] = (const float*)d_in[3 + 4*i];
        whh[i] = (const float*)d_in[4 + 4*i];
        bih[i] = (const float*)d_in[5 + 4*i];
        bhh[i] = (const float*)d_in[6 + 4*i];
    }
    const float* w1 = (const float*)d_in[19];
    const float* b1 = (const float*)d_in[20];
    const float* w2 = (const float*)d_in[21];
    const float* b2 = (const float*)d_in[22];
    float* out = (float*)d_out;

    char* ws = (char*)d_ws;
    size_t off = 0;
    auto alloc = [&](size_t bytes) -> void* {
        void* p = ws + off;
        off += (bytes + 255) & ~(size_t)255;
        return p;
    };
    f16* x0    = (f16*)alloc((size_t)MTOT*HH*2);      // layer0 input; reused as enc
    f16* x1    = (f16*)alloc((size_t)MTOT*HH*2);      // layer0 output / layer1 input
    f16* pre   = (f16*)alloc((size_t)2*MTOT*NG*2);    // pre-activations (reused per layer)
    f16* exch  = (f16*)alloc((size_t)2*TT*3072*2);    // h exchange (reused; sc1 accesses
                                                      // always hit IF so reuse is safe)
    f16* wihh[4]; for (int i=0;i<4;i++) wihh[i] = (f16*)alloc((size_t)NG*HH*2);
    f16* whhh[4]; for (int i=0;i<4;i++) whhh[i] = (f16*)alloc((size_t)NG*HDD*2);
    float* bsum = (float*)alloc((size_t)4*NG*4);
    // flags: [layer][dir][producer][t], producer-strided 4KB -> no line sharing
    unsigned* flags = (unsigned*)alloc((size_t)2*2*12*TT*4);
    f16* enc = x0;

    hipMemsetAsync(flags, 0, (size_t)2*2*12*TT*4, stream);
    for (int i=0;i<4;i++)
        cast_f32_f16_k<<<(NG*HH+255)/256,256,0,stream>>>(wih[i], wihh[i], NG*HH);
    for (int i=0;i<4;i++)
        cast_f32_f16_k<<<(NG*HDD+255)/256,256,0,stream>>>(whh[i], whhh[i], NG*HDD);
    bias_sum_k<<<(4*NG+255)/256,256,0,stream>>>(bih[0],bhh[0],bih[1],bhh[1],
                                                bih[2],bhh[2],bih[3],bhh[3],bsum);
    embed_cast_k<<<(MTOT*HH+255)/256,256,0,stream>>>(ids, emb, x0);

    dim3 gg(MTOT/64, NG/64, 2);
    gemm_pre_k<<<gg,256,0,stream>>>(x0, wihh[0], wihh[1], bsum, pre);
    lstm_layer_k<<<24,256,0,stream>>>(pre, whhh[0], whhh[1], x1, exch, flags);
    gemm_pre_k<<<gg,256,0,stream>>>(x1, wihh[2], wihh[3], bsum + 2*NG, pre);
    lstm_layer_k<<<24,256,0,stream>>>(pre, whhh[2], whhh[3], enc, exch, flags + 2*12*TT);
    pool_mlp_k<<<BB*SS,256,0,stream>>>(enc, bounds, w1, b1, w2, b2, out);
    finalize_k<<<1,64,0,stream>>>(out);
}

// Round 5
// 6810.034 us; speedup vs baseline: 1.7875x; 1.5407x over previous
//
#include <hip/hip_runtime.h>

typedef _Float16 f16;
typedef _Float16 f16x8 __attribute__((ext_vector_type(8)));
typedef float f32x4 __attribute__((ext_vector_type(4)));

#define BB 8
#define TT 1024
#define HH 768
#define HDD 384
#define NG 1536        // 4*HDD
#define SS 16
#define MTOT (BB*TT)   // 8192

// ---------------- casts ----------------
__global__ void cast_f32_f16_k(const float* __restrict__ src, f16* __restrict__ dst, int n) {
    int i = blockIdx.x*256 + threadIdx.x;
    if (i < n) dst[i] = (f16)src[i];
}

__global__ void bias_sum_k(const float* a0,const float* b0,const float* a1,const float* b1,
                           const float* a2,const float* b2,const float* a3,const float* b3,
                           float* __restrict__ out) {
    int i = blockIdx.x*256 + threadIdx.x;
    if (i >= 4*NG) return;
    int which = i/NG, j = i - which*NG;
    const float* pa = which==0?a0:which==1?a1:which==2?a2:a3;
    const float* pb = which==0?b0:which==1?b1:which==2?b2:b3;
    out[i] = pa[j] + pb[j];
}

__global__ void embed_cast_k(const int* __restrict__ ids, const float* __restrict__ emb,
                             f16* __restrict__ x) {
    int i = blockIdx.x*256 + threadIdx.x;   // < MTOT*HH
    if (i < MTOT*HH) {
        int m = i / HH;
        int k = i - m*HH;
        x[i] = (f16)emb[(size_t)ids[m]*HH + k];
    }
}

// ---------------- input GEMM (validated in R1, unchanged) ----------------
__launch_bounds__(256,1)
__global__ void gemm_pre_k(const f16* __restrict__ A, const f16* __restrict__ Wf,
                           const f16* __restrict__ Wb, const float* __restrict__ bsum2,
                           f16* __restrict__ pre) {
    int d = blockIdx.z;
    const f16* Wt = d ? Wb : Wf;
    const float* bs = bsum2 + d*NG;
    f16* out = pre + (size_t)d*MTOT*NG;
    int m0 = blockIdx.x*64, n0 = blockIdx.y*64;
    __shared__ f16 As[64*72];
    __shared__ f16 Bs[64*72];
    int tid = threadIdx.x;
    int w = tid>>6, l = tid&63;
    int lrow = l&15, lgrp = l>>4;
    int mq = (w>>1)*32, nq = (w&1)*32;
    f32x4 acc00={0,0,0,0}, acc01={0,0,0,0}, acc10={0,0,0,0}, acc11={0,0,0,0};

    for (int k0=0; k0<HH; k0+=64) {
        __syncthreads();
        #pragma unroll
        for (int r=0;r<2;r++) {
            int c = tid + 256*r;
            int row = c>>3, seg = c&7;
            *(f16x8*)(As + row*72 + seg*8) = *(const f16x8*)(A  + ((size_t)(m0+row))*HH + k0 + seg*8);
            *(f16x8*)(Bs + row*72 + seg*8) = *(const f16x8*)(Wt + ((size_t)(n0+row))*HH + k0 + seg*8);
        }
        __syncthreads();
        #pragma unroll
        for (int kk=0; kk<64; kk+=32) {
            f16x8 a0 = *(const f16x8*)(As + (mq+lrow)*72    + kk + lgrp*8);
            f16x8 a1 = *(const f16x8*)(As + (mq+16+lrow)*72 + kk + lgrp*8);
            f16x8 b0 = *(const f16x8*)(Bs + (nq+lrow)*72    + kk + lgrp*8);
            f16x8 b1 = *(const f16x8*)(Bs + (nq+16+lrow)*72 + kk + lgrp*8);
            acc00 = __builtin_amdgcn_mfma_f32_16x16x32_f16(a0,b0,acc00,0,0,0);
            acc01 = __builtin_amdgcn_mfma_f32_16x16x32_f16(a0,b1,acc01,0,0,0);
            acc10 = __builtin_amdgcn_mfma_f32_16x16x32_f16(a1,b0,acc10,0,0,0);
            acc11 = __builtin_amdgcn_mfma_f32_16x16x32_f16(a1,b1,acc11,0,0,0);
        }
    }
    #pragma unroll
    for (int mt=0;mt<2;mt++) {
        #pragma unroll
        for (int nt=0;nt<2;nt++) {
            f32x4 a = (mt==0)?(nt==0?acc00:acc01):(nt==0?acc10:acc11);
            int col = n0 + nq + nt*16 + lrow;
            float bv = bs[col];
            #pragma unroll
            for (int r=0;r<4;r++) {
                int row = m0 + mq + mt*16 + lgrp*4 + r;
                out[(size_t)row*NG + col] = (f16)(a[r] + bv);
            }
        }
    }
}

// ---- helpers ----
// sc0 load: single flag poll, intended L1-bypass/L2-read. If sc0 is actually
// scope-conveying (stale L1), the capped loop + sticky fallback handles it.
__device__ __forceinline__ unsigned ld_u32_sc0(const unsigned* p) {
    unsigned v;
    asm volatile("global_load_dword %0, %1, off sc0\n\ts_waitcnt vmcnt(0)"
                 : "=v"(v) : "v"(p) : "memory");
    return v;
}
__device__ __forceinline__ unsigned get_xcc() {
    unsigned x;
    asm("s_getreg_b32 %0, hwreg(HW_REG_XCC_ID)" : "=s"(x));
    return x & 7u;
}

// ---------------- LSTM recurrence ----------------
// R5: same-XCD election (capped) + dual-published flags + plain-L2 data path.
//  - election: grid 256; first XCD to register 24 running blocks wins CAS;
//    its first 24 role-grabbers participate, everyone else exits. All loops capped.
//  - data: plain stores (L1 write-through -> shared XCD L2), plain vector loads
//    (step-indexed addresses are FIRST-TOUCH in consumer L1 -> always fill from L2).
//  - flags: fast copy (plain store / sc0 poll, capped, sticky-disable) +
//    safe copy (agent relaxed atomics, R3-proven, capped + sticky-dead).
//  - hot spin, no s_sleep in the step loop (keeps DPM clocks up).
__launch_bounds__(256,1)
__global__ void lstm_layer_k(const f16* __restrict__ pre,
                             const f16* __restrict__ whh_f,
                             const f16* __restrict__ whh_b,
                             f16* __restrict__ xout,
                             f16* __restrict__ exch,
                             unsigned* __restrict__ flags_fast,
                             unsigned* __restrict__ flags_safe,
                             unsigned* __restrict__ elect) {
    int tid = threadIdx.x;
    __shared__ unsigned role_s;
    if (tid == 0) {
        unsigned xcc = get_xcc();
        unsigned r = __hip_atomic_fetch_add(&elect[xcc], 1u,
                        __ATOMIC_RELAXED, __HIP_MEMORY_SCOPE_AGENT);
        if (r == 23u) {                      // this XCD just reached 24 running blocks
            unsigned expected = 0u;
            __hip_atomic_compare_exchange_strong(&elect[8], &expected, xcc + 1u,
                __ATOMIC_RELAXED, __ATOMIC_RELAXED, __HIP_MEMORY_SCOPE_AGENT);
        }
        unsigned win = 0;
        for (int it = 0; it < (1<<20) && !win; ++it) {   // capped: no hang possible
            win = __hip_atomic_load(&elect[8], __ATOMIC_RELAXED, __HIP_MEMORY_SCOPE_AGENT);
            if (!win) __builtin_amdgcn_s_sleep(8);
        }
        unsigned role = 0xFFFFFFFFu;
        if (win == xcc + 1u)
            role = __hip_atomic_fetch_add(&elect[9], 1u,
                        __ATOMIC_RELAXED, __HIP_MEMORY_SCOPE_AGENT);
        role_s = role;
    }
    __syncthreads();
    unsigned role = role_s;
    if (role >= 24u) return;

    int dir = role >= 12u;
    int g   = (int)role - dir*12;
    const f16* W    = dir ? whh_b : whh_f;
    const f16* preD = pre  + (size_t)dir*MTOT*NG;
    f16* exchD      = exch + (size_t)dir*TT*3072;
    unsigned* ffD = flags_fast + dir*12*TT;
    unsigned* fsD = flags_safe + dir*12*TT;

    int w = tid>>6, l = tid&63;       // wave w == gate index (i,f,g,o)
    int lrow = l&15, lgrp = l>>4;

    // register-resident W_hh B-frags: rows = w*384 + 32g + {0..31}
    f16x8 bf0[12], bf1[12];
    {
        int row0 = w*HDD + g*32 + lrow;
        #pragma unroll
        for (int kk=0; kk<12; kk++)
            bf0[kk] = *(const f16x8*)(W + (size_t)row0*HDD + kk*32 + lgrp*8);
        int row1 = row0 + 16;
        #pragma unroll
        for (int kk=0; kk<12; kk++)
            bf1[kk] = *(const f16x8*)(W + (size_t)row1*HDD + kk*32 + lgrp*8);
    }

    __shared__ float gatesS[128*9];   // [local col][batch], stride 9 conflict-free
    int eb = tid>>5, ejh = tid&31;    // epilogue thread = (batch, jh)
    float c_state = 0.f;
    size_t exch_wr = ((size_t)g*4 + (ejh>>3))*64 + (size_t)eb*8 + (ejh&7);
    size_t mrow = (size_t)eb*TT;
    const f16* ex_base = exchD + (size_t)lgrp*64 + (size_t)lrow*8;

    int fast_ok = 1, dead = 0;        // wave-uniform sticky state

    for (int step=0; step<TT; step++) {
        int t = dir ? (TT-1-step) : step;
        // pre-activation loads issued before the poll (latency overlapped)
        const f16* prow = preD + (mrow + t)*NG + g*32 + ejh;
        f16 p0 = prow[0];
        f16 p1 = prow[HDD];
        f16 p2 = prow[2*HDD];
        f16 p3 = prow[3*HDD];

        f32x4 acc0 = {0,0,0,0}, acc1 = {0,0,0,0};
        if (step > 0) {
            unsigned got = (l < 12) ? 0u : 1u;
            if (!dead) {
                if (fast_ok) {
                    const unsigned* fp = ffD + (size_t)l*TT + (step-1);
                    for (int it=0; it<1024 && !__all(got != 0); ++it)
                        if (!got) got = ld_u32_sc0(fp);
                    if (!__all(got != 0)) fast_ok = 0;   // sticky: sc0 path broken/slow
                }
                if (!__all(got != 0)) {
                    const unsigned* sp = fsD + (size_t)l*TT + (step-1);
                    for (int it=0; it<8192 && !__all(got != 0); ++it)
                        if (!got) got = __hip_atomic_load(sp, __ATOMIC_RELAXED,
                                                          __HIP_MEMORY_SCOPE_AGENT);
                    if (!__all(got != 0)) dead = 1;      // protocol failure: free-run
                }
            }
            // plain data loads: first-touch in L1, fill from shared XCD L2.
            // lanes lrow>=8 read unwritten slack -> D rows 8..15, never used.
            const f16* ex = ex_base + (size_t)(step-1)*3072;
            #pragma unroll
            for (int kk=0; kk<12; kk++) {
                f16x8 af = *(const f16x8*)(ex + (size_t)kk*256);
                acc0 = __builtin_amdgcn_mfma_f32_16x16x32_f16(af, bf0[kk], acc0, 0,0,0);
                acc1 = __builtin_amdgcn_mfma_f32_16x16x32_f16(af, bf1[kk], acc1, 0,0,0);
            }
        }
        // stage gates (C layout: col=l&15, row=4*lgrp+r; rows>=8 garbage, not staged)
        if (lgrp < 2) {
            int col0 = 32*w + lrow;
            #pragma unroll
            for (int r=0;r<4;r++) gatesS[col0*9 + lgrp*4 + r] = acc0[r];
            int col1 = col0 + 16;
            #pragma unroll
            for (int r=0;r<4;r++) gatesS[col1*9 + lgrp*4 + r] = acc1[r];
        }
        __syncthreads();                               // gates visible to epilogue
        float xi = (float)p0 + gatesS[(ejh   )*9 + eb];
        float xf = (float)p1 + gatesS[(32+ejh)*9 + eb];
        float xg = (float)p2 + gatesS[(64+ejh)*9 + eb];
        float xo = (float)p3 + gatesS[(96+ejh)*9 + eb];
        float si = 1.f/(1.f+__expf(-xi));
        float sf = 1.f/(1.f+__expf(-xf));
        float eg = __expf(2.f*xg);  float gg = (eg-1.f)/(eg+1.f);
        float so = 1.f/(1.f+__expf(-xo));
        c_state = sf*c_state + si*gg;
        float ec = __expf(2.f*c_state); float tc = (ec-1.f)/(ec+1.f);
        float h = so*tc;
        f16 hh = (f16)h;
        // pack (even,odd) lane pair -> one 4B plain store (write-through to L2)
        unsigned short hu; __builtin_memcpy(&hu, &hh, 2);
        unsigned short pu = (unsigned short)__shfl_xor((int)hu, 1, 64);
        if ((ejh & 1) == 0) {
            unsigned pkt = (unsigned)hu | ((unsigned)pu << 16);
            *(unsigned*)(exchD + (size_t)step*3072 + exch_wr) = pkt;
        }
        xout[(mrow + t)*HH + dir*HDD + g*32 + ejh] = hh;
        __syncthreads();           // vmcnt(0) drain: exch stores ACKed in L2
        if (tid == 0) {
            ffD[(size_t)g*TT + step] = 1u;                       // fast copy (plain)
            __hip_atomic_store(fsD + (size_t)g*TT + step, 1u,
                               __ATOMIC_RELAXED, __HIP_MEMORY_SCOPE_AGENT);  // safe copy
        }
    }
}

// ---------------- segment mean pool + MLP + sigmoid ----------------
__global__ void pool_mlp_k(const f16* __restrict__ enc, const int* __restrict__ bounds,
                           const float* __restrict__ w1, const float* __restrict__ b1,
                           const float* __restrict__ w2, const float* __restrict__ b2,
                           float* __restrict__ out) {
    int b = blockIdx.x >> 4, s = blockIdx.x & 15;
    int tid = threadIdx.x;
    int e  = bounds[b*SS + s];
    int st = (s==0) ? 0 : bounds[b*SS + s - 1];
    int len = e - st; if (len < 1) len = 1;
    __shared__ float meanS[HH];
    __shared__ float hS[HDD];
    __shared__ float redS[256];
    for (int dd = tid; dd < HH; dd += 256) {
        float a = 0.f;
        for (int t = st; t < e; t++) a += (float)enc[((size_t)b*TT + t)*HH + dd];
        meanS[dd] = a / (float)len;
    }
    __syncthreads();
    for (int j = tid; j < HDD; j += 256) {
        float a = b1[j];
        const float* wr = w1 + (size_t)j*HH;
        for (int dd = 0; dd < HH; dd++) a += meanS[dd]*wr[dd];
        hS[j] = a > 0.f ? a : 0.f;
    }
    __syncthreads();
    float p = 0.f;
    for (int j = tid; j < HDD; j += 256) p += hS[j]*w2[j];
    redS[tid] = p;
    __syncthreads();
    for (int o = 128; o > 0; o >>= 1) {
        if (tid < o) redS[tid] += redS[tid+o];
        __syncthreads();
    }
    if (tid == 0) {
        float r = 1.f/(1.f+__expf(-(redS[0] + b2[0])));
        out[b*SS + s] = r;
    }
}

__global__ void finalize_k(float* __restrict__ out) {
    int b = threadIdx.x;
    if (b < BB) {
        float m = 1e30f;
        for (int s=0;s<SS;s++) {
            float r = out[b*SS+s];
            float mask = (r > 0.f) ? 1.f : 0.f;
            float v = r*mask + (1.f-mask);
            m = fminf(m, v);
        }
        out[BB*SS + b] = m;
    }
}

extern "C" void kernel_launch(void* const* d_in, const int* in_sizes, int n_in,
                              void* d_out, int out_size, void* d_ws, size_t ws_size,
                              hipStream_t stream) {
    const int*   ids    = (const int*)d_in[0];
    const int*   bounds = (const int*)d_in[1];
    const float* emb    = (const float*)d_in[2];
    const float* wih[4]; const float* whh[4]; const float* bih[4]; const float* bhh[4];
    for (int i=0;i<4;i++) {                // order: l0f, l0b, l1f, l1b
        wih[i] = (const float*)d_in[3 + 4*i];
        whh[i] = (const float*)d_in[4 + 4*i];
        bih[i] = (const float*)d_in[5 + 4*i];
        bhh[i] = (const float*)d_in[6 + 4*i];
    }
    const float* w1 = (const float*)d_in[19];
    const float* b1 = (const float*)d_in[20];
    const float* w2 = (const float*)d_in[21];
    const float* b2 = (const float*)d_in[22];
    float* out = (float*)d_out;

    char* ws = (char*)d_ws;
    size_t off = 0;
    auto alloc = [&](size_t bytes) -> void* {
        void* p = ws + off;
        off += (bytes + 255) & ~(size_t)255;
        return p;
    };
    f16* x0    = (f16*)alloc((size_t)MTOT*HH*2);      // layer0 input; reused as enc
    f16* x1    = (f16*)alloc((size_t)MTOT*HH*2);      // layer0 output / layer1 input
    f16* pre   = (f16*)alloc((size_t)2*MTOT*NG*2);    // pre-activations (reused per layer)
    f16* exch  = (f16*)alloc((size_t)2*TT*3072*2 + 4096); // h exchange (+tail-read slack)
    f16* wihh[4]; for (int i=0;i<4;i++) wihh[i] = (f16*)alloc((size_t)NG*HH*2);
    f16* whhh[4]; for (int i=0;i<4;i++) whhh[i] = (f16*)alloc((size_t)NG*HDD*2);
    float* bsum = (float*)alloc((size_t)4*NG*4);
    // flags (fast + safe): [layer][dir][producer g][t], g-stride 4KB
    unsigned* flags_fast = (unsigned*)alloc((size_t)2*2*12*TT*4);
    unsigned* flags_safe = (unsigned*)alloc((size_t)2*2*12*TT*4);
    unsigned* elect      = (unsigned*)alloc((size_t)2*16*4);
    f16* enc = x0;

    hipMemsetAsync(flags_fast, 0, (size_t)2*2*12*TT*4, stream);
    hipMemsetAsync(flags_safe, 0, (size_t)2*2*12*TT*4, stream);
    hipMemsetAsync(elect,      0, (size_t)2*16*4, stream);
    for (int i=0;i<4;i++)
        cast_f32_f16_k<<<(NG*HH+255)/256,256,0,stream>>>(wih[i], wihh[i], NG*HH);
    for (int i=0;i<4;i++)
        cast_f32_f16_k<<<(NG*HDD+255)/256,256,0,stream>>>(whh[i], whhh[i], NG*HDD);
    bias_sum_k<<<(4*NG+255)/256,256,0,stream>>>(bih[0],bhh[0],bih[1],bhh[1],
                                                bih[2],bhh[2],bih[3],bhh[3],bsum);
    embed_cast_k<<<(MTOT*HH+255)/256,256,0,stream>>>(ids, emb, x0);

    dim3 gg(MTOT/64, NG/64, 2);
    gemm_pre_k<<<gg,256,0,stream>>>(x0, wihh[0], wihh[1], bsum, pre);
    lstm_layer_k<<<256,256,0,stream>>>(pre, whhh[0], whhh[1], x1, exch,
                                       flags_fast, flags_safe, elect);
    gemm_pre_k<<<gg,256,0,stream>>>(x1, wihh[2], wihh[3], bsum + 2*NG, pre);
    lstm_layer_k<<<256,256,0,stream>>>(pre, whhh[2], whhh[3], enc, exch,
                                       flags_fast + 2*12*TT, flags_safe + 2*12*TT,
                                       elect + 16);
    pool_mlp_k<<<BB*SS,256,0,stream>>>(enc, bounds, w1, b1, w2, b2, out);
    finalize_k<<<1,64,0,stream>>>(out);
}